// Round 6
// baseline (1447.782 us; speedup 1.0000x reference)
//
#include <hip/hip_runtime.h>
#include <hip/hip_fp16.h>

#define NFEAT 64
#define CE 8192          // edges per histogram/scatter chunk (256 thr x 32)
#define NBMAX 1792       // 7*256 >= nb = ceil(N/64) = 1563

typedef _Float16 half8 __attribute__((ext_vector_type(8)));
typedef float f32x4 __attribute__((ext_vector_type(4)));

__device__ __forceinline__ __half2 bch(unsigned int u) {
    return __builtin_bit_cast(__half2, u);
}

// ---------------- prep: cvtW1 | cvtW2 | per-chunk histogram (dst>>6) -----------
__global__ __launch_bounds__(256) void k_prep(
    const float* __restrict__ W1, __half* __restrict__ Wt1,
    const float* __restrict__ W2, __half* __restrict__ Wt2,
    const int* __restrict__ eiDst, int* __restrict__ hist, int E, int nb)
{
    __shared__ int hb[NBMAX];
    int bid = blockIdx.x, tid = threadIdx.x;
    if (bid < 64) {
        int idx = bid * 256 + tid;            // [0, 16384)
        int n = idx >> 8, k = idx & 255;
        Wt1[idx] = __float2half(W1[(size_t)k * NFEAT + n]);
    } else if (bid < 80) {
        int idx = (bid - 64) * 256 + tid;     // [0, 4096)
        int n = idx >> 6, k = idx & 63;
        Wt2[idx] = __float2half(W2[(size_t)k * NFEAT + n]);
    } else {
        int c = bid - 80;
        int base = c * CE;
        if (base >= E) return;
        for (int i = tid; i < nb; i += 256) hb[i] = 0;
        __syncthreads();
        int hi = min(base + CE, E);
        for (int e = base + tid; e < hi; e += 256)
            atomicAdd(&hb[eiDst[e] >> 6], 1);
        __syncthreads();
        for (int i = tid; i < nb; i += 256)
            hist[(size_t)c * nb + i] = hb[i];
    }
}

// ---------------- scan B: per-bucket exclusive scan over chunks ----------------
__global__ __launch_bounds__(256) void k_scanB(int* __restrict__ hist,
                                               int* __restrict__ cntB,
                                               int nchk, int nb) {
    __shared__ int hb[256];
    int b = blockIdx.x, tid = threadIdx.x;
    int v = (tid < nchk) ? hist[(size_t)tid * nb + b] : 0;
    hb[tid] = v;
    __syncthreads();
    for (int off = 1; off < 256; off <<= 1) {
        int t = (tid >= off) ? hb[tid - off] : 0;
        __syncthreads();
        if (tid >= off) hb[tid] += t;
        __syncthreads();
    }
    if (tid < nchk) hist[(size_t)tid * nb + b] = hb[tid] - v;
    if (tid == 255) cntB[b] = hb[255];
}

// ---------------- scan C: bucket bases bb2[0..nb], bb2[nb] = E -----------------
__global__ __launch_bounds__(256) void k_scanC(const int* __restrict__ cntB,
                                               int* __restrict__ bb2, int nb) {
    __shared__ int hb[256];
    int tid = threadIdx.x;
    int sb = tid * 7;
    int loc[7];
    int s = 0;
#pragma unroll
    for (int j = 0; j < 7; ++j) {
        int v = (sb + j < nb) ? cntB[sb + j] : 0;
        loc[j] = s; s += v;
    }
    hb[tid] = s;
    __syncthreads();
    for (int off = 1; off < 256; off <<= 1) {
        int t = (tid >= off) ? hb[tid - off] : 0;
        __syncthreads();
        if (tid >= off) hb[tid] += t;
        __syncthreads();
    }
    int excl = hb[tid] - s;
#pragma unroll
    for (int j = 0; j < 7; ++j)
        if (sb + j < nb) bb2[sb + j] = excl + loc[j];
    if (tid == 255) bb2[nb] = hb[255];
}

// ---------------- scatter: LDS counting-sort chunk -> bucket-ordered E2 --------
__global__ __launch_bounds__(256) void k_scatter(
    const int* __restrict__ ei, const int* __restrict__ hist,
    const int* __restrict__ bb2, int2* __restrict__ E2, int E, int nb)
{
    __shared__ int2 ebuf[CE];       // 64 KB
    __shared__ int lofs[NBMAX];     // 7.2 KB
    __shared__ int cur[NBMAX];      // 7.2 KB
    __shared__ int hb[256];
    int c = blockIdx.x, tid = threadIdx.x;
    int base = c * CE, hi = min(base + CE, E), ne = hi - base;

    // 1) local histogram
    for (int i = tid; i < nb; i += 256) cur[i] = 0;
    __syncthreads();
    for (int e = base + tid; e < hi; e += 256)
        atomicAdd(&cur[ei[(size_t)E + e] >> 6], 1);
    __syncthreads();

    // 2) exclusive scan cur -> lofs (7 elems/thread + block scan)
    int sb = tid * 7;
    int loc[7];
    int s = 0;
#pragma unroll
    for (int j = 0; j < 7; ++j) {
        int v = (sb + j < nb) ? cur[sb + j] : 0;
        loc[j] = s; s += v;
    }
    hb[tid] = s;
    __syncthreads();
    for (int off = 1; off < 256; off <<= 1) {
        int t = (tid >= off) ? hb[tid - off] : 0;
        __syncthreads();
        if (tid >= off) hb[tid] += t;
        __syncthreads();
    }
    int excl = hb[tid] - s;
#pragma unroll
    for (int j = 0; j < 7; ++j)
        if (sb + j < nb) lofs[sb + j] = excl + loc[j];
    __syncthreads();

    // 3) cursors, place bucket-sorted into ebuf
    for (int i = tid; i < nb; i += 256) cur[i] = lofs[i];
    __syncthreads();
    for (int e = base + tid; e < hi; e += 256) {
        int sv = ei[e];
        int dv = ei[(size_t)E + e];
        int p = atomicAdd(&cur[dv >> 6], 1);
        ebuf[p] = make_int2(sv, dv);
    }
    __syncthreads();

    // 4) lofs[b] := global_dest_base - local_base; write out (runs coalesce)
    for (int i = tid; i < nb; i += 256)
        lofs[i] = bb2[i] + hist[(size_t)c * nb + i] - lofs[i];
    __syncthreads();
    for (int i = tid; i < ne; i += 256) {
        int2 e2 = ebuf[i];
        E2[lofs[e2.y >> 6] + i] = e2;
    }
}

// ---------------- dinv: per-64-node-bucket degree count ------------------------
__global__ __launch_bounds__(256) void k_dinv(
    const int2* __restrict__ E2, const int* __restrict__ bb2,
    float* __restrict__ dinv, int N)
{
    __shared__ int cnt[64];
    int b = blockIdx.x, tid = threadIdx.x;
    if (tid < 64) cnt[tid] = 0;
    __syncthreads();
    int e0 = bb2[b], e1 = bb2[b + 1];
    for (int e = e0 + tid; e < e1; e += 256)
        atomicAdd(&cnt[E2[e].y & 63], 1);
    __syncthreads();
    int node = b * 64 + tid;
    if (tid < 64 && node < N)
        dinv[node] = rsqrtf((float)(cnt[tid] + 1));   // +1 self-loop
}

// ---------------- layer-1 GEMM: LDS-free, barrier-free direct MFMA -------------
__global__ __launch_bounds__(256) void k_gemm1(
    const float* __restrict__ A, const __half* __restrict__ Wt,
    const float* __restrict__ dinv, __half* __restrict__ H, int M)
{
    const int K = 256;
    int tid = threadIdx.x;
    int w = tid >> 6, lane = tid & 63;
    int q = lane >> 4, n16 = lane & 15;
    int m0 = blockIdx.x * 64;

    int arow = m0 + w * 16 + n16;
    if (arow > M - 1) arow = M - 1;        // clamp: rows >= M never stored
    const float* ap = A + (size_t)arow * K + q * 8;
    const __half* wp = Wt + (size_t)n16 * K + q * 8;   // L1-hot W fragments

    f32x4 acc[4];
#pragma unroll
    for (int nt = 0; nt < 4; ++nt) acc[nt] = (f32x4)(0.f);

#pragma unroll
    for (int kt = 0; kt < 8; ++kt) {
        float4 f0 = *(const float4*)(ap + kt * 32);
        float4 f1 = *(const float4*)(ap + kt * 32 + 4);
        float fv[8] = {f0.x, f0.y, f0.z, f0.w, f1.x, f1.y, f1.z, f1.w};
        half8 ahi, alo;
#pragma unroll
        for (int j = 0; j < 8; ++j) {
            _Float16 hi = (_Float16)fv[j];
            ahi[j] = hi;
            alo[j] = (_Float16)(fv[j] - (float)hi);
        }
#pragma unroll
        for (int nt = 0; nt < 4; ++nt) {
            uint4 u = *(const uint4*)(wp + (size_t)(nt * 16) * K + kt * 32);
            half8 b = __builtin_bit_cast(half8, u);
            acc[nt] = __builtin_amdgcn_mfma_f32_16x16x32_f16(ahi, b, acc[nt], 0, 0, 0);
            acc[nt] = __builtin_amdgcn_mfma_f32_16x16x32_f16(alo, b, acc[nt], 0, 0, 0);
        }
    }

#pragma unroll
    for (int reg = 0; reg < 4; ++reg) {
        int row = m0 + w * 16 + q * 4 + reg;
        if (row < M) {
            float di = dinv[row];
#pragma unroll
            for (int nt = 0; nt < 4; ++nt)
                H[(size_t)row * NFEAT + nt * 16 + n16] =
                    __float2half(di * acc[nt][reg]);
        }
    }
}

// ---------------- EDGE-CENTRIC layer-1 aggregate + layer-2 GEMM ----------------
// One block per 64-node bucket. Threads sweep the bucket's E2 range UNIFORMLY
// (no per-row degree divergence -- the old 8-lane-slot row loop ran at the max
// of 8 Poisson(16) degrees, ~2x the mean). 8-lane slot gathers h1[src] (128B),
// ds_add_f32 into acc[dst&63][f] ([68] stride spreads atomic banks). Epilogue:
// self + bias + relu in place, then K=64 MFMA from LDS -> H2.
__global__ __launch_bounds__(256) void k_ag1g2(
    const __half* __restrict__ h, const int2* __restrict__ E2,
    const int* __restrict__ bb2, const float* __restrict__ dinv,
    const float* __restrict__ b1, const __half* __restrict__ Wt2,
    __half* __restrict__ H2, int n)
{
    __shared__ float acc[64][68];   // 17.4 KB
    int tid = threadIdx.x;
    int b = blockIdx.x;
    for (int i = tid; i < 64 * 68; i += 256) ((float*)acc)[i] = 0.f;
    __syncthreads();

    int slot = tid >> 3, li = tid & 7, fi = li << 3;
    const __half* hp = h + fi;
    int e0 = bb2[b], e1 = bb2[b + 1];

    auto accum = [&](int2 ed) {
        uint4 u = *(const uint4*)(hp + (size_t)ed.x * NFEAT);
        float* ar = &acc[ed.y & 63][fi];
        float2 f0 = __half22float2(bch(u.x));
        float2 f1 = __half22float2(bch(u.y));
        float2 f2 = __half22float2(bch(u.z));
        float2 f3 = __half22float2(bch(u.w));
        atomicAdd(ar + 0, f0.x); atomicAdd(ar + 1, f0.y);
        atomicAdd(ar + 2, f1.x); atomicAdd(ar + 3, f1.y);
        atomicAdd(ar + 4, f2.x); atomicAdd(ar + 5, f2.y);
        atomicAdd(ar + 6, f3.x); atomicAdd(ar + 7, f3.y);
    };
    int e = e0 + slot;
    for (; e + 32 < e1; e += 64) {          // 2 edges in flight per lane
        int2 ea = E2[e];
        int2 eb = E2[e + 32];
        accum(ea);
        accum(eb);
    }
    if (e < e1) accum(E2[e]);
    __syncthreads();

    // epilogue A: acc[lr][f] = relu(b1 + dinv*(acc + self))
#pragma unroll
    for (int hf = 0; hf < 2; ++hf) {
        int lr = hf * 32 + slot;
        int r = b * 64 + lr;
        if (r < n) {
            uint4 us = *(const uint4*)(hp + (size_t)r * NFEAT);
            float2 s0 = __half22float2(bch(us.x));
            float2 s1 = __half22float2(bch(us.y));
            float2 s2 = __half22float2(bch(us.z));
            float2 s3 = __half22float2(bch(us.w));
            float di = dinv[r];
            float* ar = &acc[lr][fi];
            ar[0] = fmaxf(b1[fi + 0] + di * (ar[0] + s0.x), 0.f);
            ar[1] = fmaxf(b1[fi + 1] + di * (ar[1] + s0.y), 0.f);
            ar[2] = fmaxf(b1[fi + 2] + di * (ar[2] + s1.x), 0.f);
            ar[3] = fmaxf(b1[fi + 3] + di * (ar[3] + s1.y), 0.f);
            ar[4] = fmaxf(b1[fi + 4] + di * (ar[4] + s2.x), 0.f);
            ar[5] = fmaxf(b1[fi + 5] + di * (ar[5] + s2.y), 0.f);
            ar[6] = fmaxf(b1[fi + 6] + di * (ar[6] + s3.x), 0.f);
            ar[7] = fmaxf(b1[fi + 7] + di * (ar[7] + s3.y), 0.f);
        }
    }
    __syncthreads();

    // epilogue B: K=64 MFMA from LDS
    int w = tid >> 6, lane = tid & 63;
    int q = lane >> 4, n16 = lane & 15;
    f32x4 oacc[4];
#pragma unroll
    for (int nt = 0; nt < 4; ++nt) oacc[nt] = (f32x4)(0.f);
    const __half* wp = Wt2 + (size_t)n16 * 64 + q * 8;

#pragma unroll
    for (int kt = 0; kt < 2; ++kt) {
        const float* ap = &acc[w * 16 + n16][kt * 32 + q * 8];
        float4 f0 = *(const float4*)ap;
        float4 f1 = *(const float4*)(ap + 4);
        float fv[8] = {f0.x, f0.y, f0.z, f0.w, f1.x, f1.y, f1.z, f1.w};
        half8 ahi, alo;
#pragma unroll
        for (int j = 0; j < 8; ++j) {
            _Float16 hi = (_Float16)fv[j];
            ahi[j] = hi;
            alo[j] = (_Float16)(fv[j] - (float)hi);
        }
#pragma unroll
        for (int nt = 0; nt < 4; ++nt) {
            uint4 u = *(const uint4*)(wp + (size_t)(nt * 16) * 64 + kt * 32);
            half8 bb = __builtin_bit_cast(half8, u);
            oacc[nt] = __builtin_amdgcn_mfma_f32_16x16x32_f16(ahi, bb, oacc[nt], 0, 0, 0);
            oacc[nt] = __builtin_amdgcn_mfma_f32_16x16x32_f16(alo, bb, oacc[nt], 0, 0, 0);
        }
    }
#pragma unroll
    for (int reg = 0; reg < 4; ++reg) {
        int row = b * 64 + w * 16 + q * 4 + reg;
        if (row < n) {
            float di = dinv[row];
#pragma unroll
            for (int nt = 0; nt < 4; ++nt)
                H2[(size_t)row * NFEAT + nt * 16 + n16] =
                    __float2half(di * oacc[nt][reg]);
        }
    }
}

// ---------------- EDGE-CENTRIC layer-2 aggregate + relu + FC -> out ------------
__global__ __launch_bounds__(256) void k_out(
    const __half* __restrict__ h2, const int2* __restrict__ E2,
    const int* __restrict__ bb2, const float* __restrict__ dinv,
    const float* __restrict__ b2, const float* __restrict__ Wfc,
    const float* __restrict__ bfc, float* __restrict__ out, int n)
{
    __shared__ float acc[64][68];
    __shared__ float Wl[NFEAT * 11 + 11];
    int tid = threadIdx.x;
    int b = blockIdx.x;
    for (int i = tid; i < 64 * 68; i += 256) ((float*)acc)[i] = 0.f;
    for (int i = tid; i < NFEAT * 11; i += 256) Wl[i] = Wfc[i];
    if (tid < 11) Wl[NFEAT * 11 + tid] = bfc[tid];
    __syncthreads();

    int slot = tid >> 3, li = tid & 7, fi = li << 3;
    const __half* hp = h2 + fi;
    int e0 = bb2[b], e1 = bb2[b + 1];

    auto accum = [&](int2 ed) {
        uint4 u = *(const uint4*)(hp + (size_t)ed.x * NFEAT);
        float* ar = &acc[ed.y & 63][fi];
        float2 f0 = __half22float2(bch(u.x));
        float2 f1 = __half22float2(bch(u.y));
        float2 f2 = __half22float2(bch(u.z));
        float2 f3 = __half22float2(bch(u.w));
        atomicAdd(ar + 0, f0.x); atomicAdd(ar + 1, f0.y);
        atomicAdd(ar + 2, f1.x); atomicAdd(ar + 3, f1.y);
        atomicAdd(ar + 4, f2.x); atomicAdd(ar + 5, f2.y);
        atomicAdd(ar + 6, f3.x); atomicAdd(ar + 7, f3.y);
    };
    int e = e0 + slot;
    for (; e + 32 < e1; e += 64) {
        int2 ea = E2[e];
        int2 eb = E2[e + 32];
        accum(ea);
        accum(eb);
    }
    if (e < e1) accum(E2[e]);
    __syncthreads();

#pragma unroll
    for (int hf = 0; hf < 2; ++hf) {
        int lr = hf * 32 + slot;
        int r = b * 64 + lr;
        if (r < n) {                         // slot-uniform: shfl partners stay in-slot
            uint4 us = *(const uint4*)(hp + (size_t)r * NFEAT);
            float2 s0 = __half22float2(bch(us.x));
            float2 s1 = __half22float2(bch(us.y));
            float2 s2 = __half22float2(bch(us.z));
            float2 s3 = __half22float2(bch(us.w));
            float di = dinv[r];
            const float* ar = &acc[lr][fi];
            float t0 = fmaxf(b2[fi + 0] + di * (ar[0] + s0.x), 0.f);
            float t1 = fmaxf(b2[fi + 1] + di * (ar[1] + s0.y), 0.f);
            float t2 = fmaxf(b2[fi + 2] + di * (ar[2] + s1.x), 0.f);
            float t3 = fmaxf(b2[fi + 3] + di * (ar[3] + s1.y), 0.f);
            float t4 = fmaxf(b2[fi + 4] + di * (ar[4] + s2.x), 0.f);
            float t5 = fmaxf(b2[fi + 5] + di * (ar[5] + s2.y), 0.f);
            float t6 = fmaxf(b2[fi + 6] + di * (ar[6] + s3.x), 0.f);
            float t7 = fmaxf(b2[fi + 7] + di * (ar[7] + s3.y), 0.f);
#pragma unroll
            for (int c = 0; c < 11; ++c) {
                const float* wc = &Wl[fi * 11 + c];
                float p = t0 * wc[0] + t1 * wc[11] + t2 * wc[22] + t3 * wc[33]
                        + t4 * wc[44] + t5 * wc[55] + t6 * wc[66] + t7 * wc[77];
                p += __shfl_xor(p, 1, 64);
                p += __shfl_xor(p, 2, 64);
                p += __shfl_xor(p, 4, 64);
                if (li == 0) out[(size_t)r * 11 + c] = p + Wl[NFEAT * 11 + c];
            }
        }
    }
}

extern "C" void kernel_launch(void* const* d_in, const int* in_sizes, int n_in,
                              void* d_out, int out_size, void* d_ws, size_t ws_size,
                              hipStream_t stream) {
    const float* x   = (const float*)d_in[0];
    const int*   ei  = (const int*)d_in[1];
    const float* W1  = (const float*)d_in[2];
    const float* b1  = (const float*)d_in[3];
    const float* W2  = (const float*)d_in[4];
    const float* b2  = (const float*)d_in[5];
    const float* Wfc = (const float*)d_in[6];
    const float* bfc = (const float*)d_in[7];
    float* out = (float*)d_out;

    const int Fin = 256;
    int N = in_sizes[0] / Fin;      // 100000
    int E = in_sizes[1] / 2;        // 1600000

    char* ws = (char*)d_ws;
    size_t off = 0;
    auto alloc = [&](size_t bytes) { void* p = ws + off; off = (off + bytes + 255) & ~(size_t)255; return p; };
    float*  dinv   = (float*) alloc((size_t)N * 4);
    __half* Wt1    = (__half*)alloc((size_t)64 * 256 * 2);
    __half* Wt2    = (__half*)alloc((size_t)64 * 64 * 2);
    __half* A      = (__half*)alloc((size_t)N * NFEAT * 2);  // h1 (dinv-prescaled)
    __half* H2     = (__half*)alloc((size_t)N * NFEAT * 2);  // h2 (dinv-prescaled)

    int nb   = (N + 63) >> 6;                   // 1563 buckets of 64 nodes
    int NCHK = (E + CE - 1) / CE;               // 196 chunks of 8192 edges

    int2* E2   = (int2*)alloc((size_t)E * 8);   // bucket-ordered (src,dst)
    int*  hist = (int*) alloc((size_t)NCHK * nb * 4);
    int*  cntB = (int*) alloc((size_t)nb * 4);
    int*  bb2  = (int*) alloc((size_t)(nb + 1) * 4);

    // prep: W converts + per-chunk histograms (no global atomics anywhere)
    k_prep<<<80 + NCHK, 256, 0, stream>>>(W1, Wt1, W2, Wt2, ei + E, hist, E, nb);

    // bucket-sort chain
    k_scanB<<<nb, 256, 0, stream>>>(hist, cntB, NCHK, nb);
    k_scanC<<<1, 256, 0, stream>>>(cntB, bb2, nb);
    k_scatter<<<NCHK, 256, 0, stream>>>(ei, hist, bb2, E2, E, nb);
    k_dinv<<<nb, 256, 0, stream>>>(E2, bb2, dinv, N);

    // layer 1 GEMM (LDS-free, barrier-free): A = fp16(dinv .* (x @ W1))
    k_gemm1<<<nb, 256, 0, stream>>>(x, Wt1, dinv, A, N);

    // edge-centric layer-1 aggregate + layer-2 GEMM
    k_ag1g2<<<nb, 256, 0, stream>>>(A, E2, bb2, dinv, b1, Wt2, H2, N);

    // edge-centric layer-2 aggregate + relu + FC -> out
    k_out<<<nb, 256, 0, stream>>>(H2, E2, bb2, dinv, b2, Wfc, bfc, out, N);
}

// Round 7
// 334.837 us; speedup vs baseline: 4.3238x; 4.3238x over previous
//
#include <hip/hip_runtime.h>
#include <hip/hip_fp16.h>

#define NFEAT 64
#define CE 8192          // edges per histogram/scatter chunk (256 thr x 32)
#define EBUF 4608        // LDS-staged edges per bucket in k_csr

typedef _Float16 half8 __attribute__((ext_vector_type(8)));
typedef float f32x4 __attribute__((ext_vector_type(4)));

__device__ __forceinline__ __half2 bch(unsigned int u) {
    return __builtin_bit_cast(__half2, u);
}

// ---------------- prep: cvtW1 | cvtW2 | per-chunk histogram --------------------
__global__ __launch_bounds__(256) void k_prep(
    const float* __restrict__ W1, __half* __restrict__ Wt1,
    const float* __restrict__ W2, __half* __restrict__ Wt2,
    const int* __restrict__ eiDst, int* __restrict__ hist, int E, int nbkt)
{
    __shared__ int hb[512];
    int bid = blockIdx.x, tid = threadIdx.x;
    if (bid < 64) {
        int idx = bid * 256 + tid;            // [0, 16384)
        int n = idx >> 8, k = idx & 255;
        Wt1[idx] = __float2half(W1[(size_t)k * NFEAT + n]);
    } else if (bid < 80) {
        int idx = (bid - 64) * 256 + tid;     // [0, 4096)
        int n = idx >> 6, k = idx & 63;
        Wt2[idx] = __float2half(W2[(size_t)k * NFEAT + n]);
    } else {
        int c = bid - 80;
        int base = c * CE;
        if (base >= E) return;
        for (int i = tid; i < nbkt; i += 256) hb[i] = 0;
        __syncthreads();
        int hi = min(base + CE, E);
        for (int e = base + tid; e < hi; e += 256)
            atomicAdd(&hb[eiDst[e] >> 8], 1);
        __syncthreads();
        for (int i = tid; i < nbkt; i += 256)
            hist[(size_t)c * nbkt + i] = hb[i];
    }
}

// ---------------- scan B: per-bucket exclusive scan over chunks ----------------
__global__ __launch_bounds__(256) void k_scanB(int* __restrict__ hist,
                                               int* __restrict__ cntB,
                                               int nchk, int nbkt) {
    __shared__ int hb[256];
    int b = blockIdx.x, tid = threadIdx.x;
    int v = (tid < nchk) ? hist[(size_t)tid * nbkt + b] : 0;
    hb[tid] = v;
    __syncthreads();
    for (int off = 1; off < 256; off <<= 1) {
        int t = (tid >= off) ? hb[tid - off] : 0;
        __syncthreads();
        if (tid >= off) hb[tid] += t;
        __syncthreads();
    }
    if (tid < nchk) hist[(size_t)tid * nbkt + b] = hb[tid] - v;
    if (tid == 255) cntB[b] = hb[255];
}

// ---------------- scatter: LDS counting-sort chunk -> coalesced E2 writes ------
__global__ __launch_bounds__(256) void k_scatter(
    const int* __restrict__ ei, const int* __restrict__ hist,
    const int* __restrict__ cntB, int2* __restrict__ E2, int E, int nbkt)
{
    __shared__ int2 ebuf[CE];       // 64 KB
    __shared__ int lofs[512];       // local (in-chunk) exclusive bucket offsets
    __shared__ int gbase[512];      // global dest base per bucket
    __shared__ int cur[512];        // cursors / local histogram
    __shared__ int hb[256];
    int c = blockIdx.x, tid = threadIdx.x;
    int base = c * CE, hi = min(base + CE, E), ne = hi - base;

    // 1) local histogram into cur
    for (int i = tid; i < nbkt; i += 256) cur[i] = 0;
    __syncthreads();
    for (int e = base + tid; e < hi; e += 256)
        atomicAdd(&cur[ei[(size_t)E + e] >> 8], 1);
    __syncthreads();

    // 2) scan local histogram -> lofs (exclusive)
    int i0 = 2 * tid, i1 = 2 * tid + 1;
    int a0 = (i0 < nbkt) ? cur[i0] : 0;
    int a1 = (i1 < nbkt) ? cur[i1] : 0;
    hb[tid] = a0 + a1;
    __syncthreads();
    for (int off = 1; off < 256; off <<= 1) {
        int t = (tid >= off) ? hb[tid - off] : 0;
        __syncthreads();
        if (tid >= off) hb[tid] += t;
        __syncthreads();
    }
    int excl = hb[tid] - (a0 + a1);
    if (i0 < nbkt) lofs[i0] = excl;
    if (i1 < nbkt) lofs[i1] = excl + a0;

    // 3) scan cntB -> bucket bases; gbase[b] = bb[b] + hist_excl[c][b]
    int b0 = (i0 < nbkt) ? cntB[i0] : 0;
    int b1 = (i1 < nbkt) ? cntB[i1] : 0;
    hb[tid] = b0 + b1;
    __syncthreads();
    for (int off = 1; off < 256; off <<= 1) {
        int t = (tid >= off) ? hb[tid - off] : 0;
        __syncthreads();
        if (tid >= off) hb[tid] += t;
        __syncthreads();
    }
    int excl2 = hb[tid] - (b0 + b1);
    if (i0 < nbkt) gbase[i0] = excl2 + hist[(size_t)c * nbkt + i0];
    if (i1 < nbkt) gbase[i1] = excl2 + b0 + hist[(size_t)c * nbkt + i1];

    // 4) place edges into ebuf bucket-sorted (cursors = lofs copy)
    for (int i = tid; i < nbkt; i += 256) cur[i] = lofs[i];
    __syncthreads();
    for (int e = base + tid; e < hi; e += 256) {
        int s = ei[e];
        int d = ei[(size_t)E + e];
        int p = atomicAdd(&cur[d >> 8], 1);
        ebuf[p] = make_int2(s, d);
    }
    __syncthreads();

    // 5) coalesced write-out: consecutive i in a bucket -> consecutive global
    for (int i = tid; i < ne; i += 256) {
        int2 e = ebuf[i];
        int b = e.y >> 8;
        E2[gbase[b] + (i - lofs[b])] = e;
    }
}

// ---------------- csr: per-bucket CSR build + dinv -----------------------------
__global__ __launch_bounds__(256) void k_csr(
    const int2* __restrict__ E2, const int* __restrict__ cntB,
    int* __restrict__ rowptr, float* __restrict__ dinv, int* __restrict__ col,
    int N, int E, int nbkt)
{
    __shared__ int2 ebuf[EBUF];     // 36.9 KB
    __shared__ int cnt[256];
    __shared__ float dl[256];
    __shared__ int bbL[512];
    __shared__ int hb[256];
    int b = blockIdx.x, tid = threadIdx.x;

    // bucket-base scan
    int i0 = 2 * tid, i1 = 2 * tid + 1;
    int a0 = (i0 < nbkt) ? cntB[i0] : 0;
    int a1 = (i1 < nbkt) ? cntB[i1] : 0;
    hb[tid] = a0 + a1;
    __syncthreads();
    for (int off = 1; off < 256; off <<= 1) {
        int t = (tid >= off) ? hb[tid - off] : 0;
        __syncthreads();
        if (tid >= off) hb[tid] += t;
        __syncthreads();
    }
    int excl = hb[tid] - (a0 + a1);
    if (i0 < nbkt) bbL[i0] = excl;
    if (i1 < nbkt) bbL[i1] = excl + a0;
    __syncthreads();

    int e0 = bbL[b];
    int e1 = (b == nbkt - 1) ? E : bbL[b + 1];
    int ne = e1 - e0;
    int nL = min(ne, EBUF);

    cnt[tid] = 0;
    __syncthreads();
    for (int i = tid; i < nL; i += 256) {
        int2 e = E2[e0 + i];
        ebuf[i] = e;
        atomicAdd(&cnt[e.y & 255], 1);
    }
    for (int i = nL + tid; i < ne; i += 256) {        // overflow (p ~ 0)
        int2 e = E2[e0 + i];
        atomicAdd(&cnt[e.y & 255], 1);
    }
    __syncthreads();
    int c = cnt[tid];
    dl[tid] = rsqrtf((float)(c + 1));                  // +1 self-loop
    for (int off = 1; off < 256; off <<= 1) {
        int t = (tid >= off) ? cnt[tid - off] : 0;
        __syncthreads();
        if (tid >= off) cnt[tid] += t;
        __syncthreads();
    }
    int texcl = cnt[tid] - c;
    int node = b * 256 + tid;
    if (node < N) {
        rowptr[node] = e0 + texcl;
        dinv[node] = dl[tid];
    }
    if (b == 0 && tid == 0) rowptr[N] = E;
    __syncthreads();
    cnt[tid] = texcl;                                  // placement cursor
    __syncthreads();
    for (int i = tid; i < nL; i += 256) {
        int2 e = ebuf[i];
        int p = atomicAdd(&cnt[e.y & 255], 1);
        col[e0 + p] = e.x;
    }
    for (int i = nL + tid; i < ne; i += 256) {
        int2 e = E2[e0 + i];
        int p = atomicAdd(&cnt[e.y & 255], 1);
        col[e0 + p] = e.x;
    }
}

// ---------------- layer-1 GEMM: LDS-free, barrier-free direct MFMA -------------
__global__ __launch_bounds__(256) void k_gemm1(
    const float* __restrict__ A, const __half* __restrict__ Wt,
    const float* __restrict__ dinv, __half* __restrict__ H, int M)
{
    const int K = 256;
    int tid = threadIdx.x;
    int w = tid >> 6, lane = tid & 63;
    int q = lane >> 4, n16 = lane & 15;
    int m0 = blockIdx.x * 64;

    int arow = m0 + w * 16 + n16;
    if (arow > M - 1) arow = M - 1;        // clamp: rows >= M never stored
    const float* ap = A + (size_t)arow * K + q * 8;
    const __half* wp = Wt + (size_t)n16 * K + q * 8;   // L1-hot W fragments

    f32x4 acc[4];
#pragma unroll
    for (int nt = 0; nt < 4; ++nt) acc[nt] = (f32x4)(0.f);

#pragma unroll
    for (int kt = 0; kt < 8; ++kt) {
        float4 f0 = *(const float4*)(ap + kt * 32);
        float4 f1 = *(const float4*)(ap + kt * 32 + 4);
        float fv[8] = {f0.x, f0.y, f0.z, f0.w, f1.x, f1.y, f1.z, f1.w};
        half8 ahi, alo;
#pragma unroll
        for (int j = 0; j < 8; ++j) {
            _Float16 hi = (_Float16)fv[j];
            ahi[j] = hi;
            alo[j] = (_Float16)(fv[j] - (float)hi);
        }
#pragma unroll
        for (int nt = 0; nt < 4; ++nt) {
            uint4 u = *(const uint4*)(wp + (size_t)(nt * 16) * K + kt * 32);
            half8 b = __builtin_bit_cast(half8, u);
            acc[nt] = __builtin_amdgcn_mfma_f32_16x16x32_f16(ahi, b, acc[nt], 0, 0, 0);
            acc[nt] = __builtin_amdgcn_mfma_f32_16x16x32_f16(alo, b, acc[nt], 0, 0, 0);
        }
    }

#pragma unroll
    for (int reg = 0; reg < 4; ++reg) {
        int row = m0 + w * 16 + q * 4 + reg;
        if (row < M) {
            float di = dinv[row];
#pragma unroll
            for (int nt = 0; nt < 4; ++nt)
                H[(size_t)row * NFEAT + nt * 16 + n16] =
                    __float2half(di * acc[nt][reg]);
        }
    }
}

// ---------------- FUSED: layer-1 aggregate (into LDS) + layer-2 GEMM -----------
// DEGREE-SORTED SLOT ASSIGNMENT: the slot->row map is arbitrary (gather writes
// Bs[lr] by row index), so we rank-sort the block's 64 rows by degree and give
// each wave's 8 slots consecutive sorted rows. A wave then runs at max of 8
// NEARLY-EQUAL degrees instead of max of 8 iid Poisson(16) (~1.35x penalty).
__global__ __launch_bounds__(256) void k_ag1g2(
    const __half* __restrict__ h, const int* __restrict__ rowptr,
    const int* __restrict__ col, const float* __restrict__ dinv,
    const float* __restrict__ b1, const __half* __restrict__ Wt2,
    __half* __restrict__ H2, int n)
{
    __shared__ float Bs[64][68];    // 17.4 KB, stride 68 -> b128 quad-bank-clean
    __shared__ int dsrt[64];        // degrees
    __shared__ int sidx[64];        // sorted-position -> local row
    __shared__ int rpb[65];
    int tid = threadIdx.x;
    int w = tid >> 6, lane = tid & 63;
    int li = lane & 7, fi = li << 3;
    int slot = (w << 3) | (lane >> 3);

    // load rowptr for the block's 64 rows + degree
    if (tid < 65) {
        int r = blockIdx.x * 64 + tid;
        rpb[tid] = rowptr[min(r, n)];
    }
    __syncthreads();
    if (tid < 64) {
        int r = blockIdx.x * 64 + tid;
        dsrt[tid] = (r < n) ? (rpb[tid + 1] - rpb[tid]) : 0;
    }
    __syncthreads();
    if (tid < 64) {
        int d = dsrt[tid];
        int rank = 0;
#pragma unroll 8
        for (int j = 0; j < 64; ++j) {
            int dj = dsrt[j];
            rank += (dj < d) || (dj == d && j < tid);
        }
        sidx[rank] = tid;
    }
    __syncthreads();

    const __half* hp = h + fi;
    auto ld = [&](int src) { return *(const uint4*)(hp + (size_t)src * NFEAT); };

#pragma unroll
    for (int hf = 0; hf < 2; ++hf) {
        int lr = sidx[hf * 32 + slot];
        int r = blockIdx.x * 64 + lr;
        float t0 = 0.f, t1 = 0.f, t2 = 0.f, t3 = 0.f,
              t4 = 0.f, t5 = 0.f, t6 = 0.f, t7 = 0.f;
        if (r < n) {
            float a0 = 0.f, a1 = 0.f, a2 = 0.f, a3 = 0.f,
                  a4 = 0.f, a5 = 0.f, a6 = 0.f, a7 = 0.f;
            auto addu = [&](uint4 u) {
                float2 f0 = __half22float2(bch(u.x));
                float2 f1 = __half22float2(bch(u.y));
                float2 f2 = __half22float2(bch(u.z));
                float2 f3 = __half22float2(bch(u.w));
                a0 += f0.x; a1 += f0.y; a2 += f1.x; a3 += f1.y;
                a4 += f2.x; a5 += f2.y; a6 += f3.x; a7 += f3.y;
            };
            auto p2 = [&](uint4 u0, uint4 u1) {
                uint4 s;
                s.x = __builtin_bit_cast(unsigned int, __hadd2(bch(u0.x), bch(u1.x)));
                s.y = __builtin_bit_cast(unsigned int, __hadd2(bch(u0.y), bch(u1.y)));
                s.z = __builtin_bit_cast(unsigned int, __hadd2(bch(u0.z), bch(u1.z)));
                s.w = __builtin_bit_cast(unsigned int, __hadd2(bch(u0.w), bch(u1.w)));
                addu(s);
            };
            int beg = rpb[lr], end = rpb[lr + 1];
            addu(ld(r));                                   // self-loop
            int j = beg;
            for (; j + 3 < end; j += 4) {                  // 4 loads in flight
                uint4 u0 = ld(col[j]);
                uint4 u1 = ld(col[j + 1]);
                uint4 u2 = ld(col[j + 2]);
                uint4 u3 = ld(col[j + 3]);
                p2(u0, u1);
                p2(u2, u3);
            }
            for (; j < end; ++j) addu(ld(col[j]));
            float di = dinv[r];
            t0 = fmaxf(b1[fi + 0] + di * a0, 0.f);
            t1 = fmaxf(b1[fi + 1] + di * a1, 0.f);
            t2 = fmaxf(b1[fi + 2] + di * a2, 0.f);
            t3 = fmaxf(b1[fi + 3] + di * a3, 0.f);
            t4 = fmaxf(b1[fi + 4] + di * a4, 0.f);
            t5 = fmaxf(b1[fi + 5] + di * a5, 0.f);
            t6 = fmaxf(b1[fi + 6] + di * a6, 0.f);
            t7 = fmaxf(b1[fi + 7] + di * a7, 0.f);
        }
        *(float4*)&Bs[lr][fi]     = make_float4(t0, t1, t2, t3);
        *(float4*)&Bs[lr][fi + 4] = make_float4(t4, t5, t6, t7);
    }
    __syncthreads();

    // ---- phase 2: 16 rows per wave, K=64 from LDS ----
    int q = lane >> 4, n16 = lane & 15;
    f32x4 acc[4];
#pragma unroll
    for (int nt = 0; nt < 4; ++nt) acc[nt] = (f32x4)(0.f);
    const __half* wp = Wt2 + (size_t)n16 * 64 + q * 8;

#pragma unroll
    for (int kt = 0; kt < 2; ++kt) {
        const float* ap = &Bs[w * 16 + n16][kt * 32 + q * 8];
        float4 f0 = *(const float4*)ap;
        float4 f1 = *(const float4*)(ap + 4);
        float fv[8] = {f0.x, f0.y, f0.z, f0.w, f1.x, f1.y, f1.z, f1.w};
        half8 ahi, alo;
#pragma unroll
        for (int j = 0; j < 8; ++j) {
            _Float16 hi = (_Float16)fv[j];
            ahi[j] = hi;
            alo[j] = (_Float16)(fv[j] - (float)hi);
        }
#pragma unroll
        for (int nt = 0; nt < 4; ++nt) {
            uint4 u = *(const uint4*)(wp + (size_t)(nt * 16) * 64 + kt * 32);
            half8 b = __builtin_bit_cast(half8, u);
            acc[nt] = __builtin_amdgcn_mfma_f32_16x16x32_f16(ahi, b, acc[nt], 0, 0, 0);
            acc[nt] = __builtin_amdgcn_mfma_f32_16x16x32_f16(alo, b, acc[nt], 0, 0, 0);
        }
    }
#pragma unroll
    for (int reg = 0; reg < 4; ++reg) {
        int row = blockIdx.x * 64 + w * 16 + q * 4 + reg;
        if (row < n) {
            float di = dinv[row];
#pragma unroll
            for (int nt = 0; nt < 4; ++nt)
                H2[(size_t)row * NFEAT + nt * 16 + n16] =
                    __float2half(di * acc[nt][reg]);
        }
    }
}

// ---------------- layer-2 aggregate + relu + FC -> out [N,11] ------------------
// Same degree-sorted slot assignment over the block's 32 rows.
__global__ __launch_bounds__(256) void k_aggr2(
    const __half* __restrict__ h, const int* __restrict__ rowptr,
    const int* __restrict__ col, const float* __restrict__ dinv,
    const float* __restrict__ bias, const float* __restrict__ Wfc,
    const float* __restrict__ bfc, float* __restrict__ out, int n)
{
    __shared__ float Wl[NFEAT * 11 + 11];
    __shared__ int dsrt[32];
    __shared__ int sidx[32];
    __shared__ int rpb[33];
    int tid = threadIdx.x;
    for (int i = tid; i < NFEAT * 11; i += 256) Wl[i] = Wfc[i];
    if (tid < 11) Wl[NFEAT * 11 + tid] = bfc[tid];
    if (tid < 33) {
        int r = blockIdx.x * 32 + tid;
        rpb[tid] = rowptr[min(r, n)];
    }
    __syncthreads();
    if (tid < 32) {
        int r = blockIdx.x * 32 + tid;
        dsrt[tid] = (r < n) ? (rpb[tid + 1] - rpb[tid]) : 0;
    }
    __syncthreads();
    if (tid < 32) {
        int d = dsrt[tid];
        int rank = 0;
#pragma unroll 8
        for (int j = 0; j < 32; ++j) {
            int dj = dsrt[j];
            rank += (dj < d) || (dj == d && j < tid);
        }
        sidx[rank] = tid;
    }
    __syncthreads();

    int lane = tid & 63;
    int li = lane & 7;
    int fi = li << 3;
    int lr = sidx[((tid >> 6) << 3) + (lane >> 3)];
    int r = blockIdx.x * 32 + lr;
    bool valid = r < n;

    int beg = 0, end = 0;
    if (valid) { beg = rpb[lr]; end = rpb[lr + 1]; }

    const __half* hp = h + fi;
    auto ld = [&](int src) { return *(const uint4*)(hp + (size_t)src * NFEAT); };

    float a0 = 0.f, a1 = 0.f, a2 = 0.f, a3 = 0.f,
          a4 = 0.f, a5 = 0.f, a6 = 0.f, a7 = 0.f;
    auto addu = [&](uint4 u) {
        float2 f0 = __half22float2(bch(u.x));
        float2 f1 = __half22float2(bch(u.y));
        float2 f2 = __half22float2(bch(u.z));
        float2 f3 = __half22float2(bch(u.w));
        a0 += f0.x; a1 += f0.y; a2 += f1.x; a3 += f1.y;
        a4 += f2.x; a5 += f2.y; a6 += f3.x; a7 += f3.y;
    };
    auto p2 = [&](uint4 u0, uint4 u1) {
        uint4 s;
        s.x = __builtin_bit_cast(unsigned int, __hadd2(bch(u0.x), bch(u1.x)));
        s.y = __builtin_bit_cast(unsigned int, __hadd2(bch(u0.y), bch(u1.y)));
        s.z = __builtin_bit_cast(unsigned int, __hadd2(bch(u0.z), bch(u1.z)));
        s.w = __builtin_bit_cast(unsigned int, __hadd2(bch(u0.w), bch(u1.w)));
        addu(s);
    };

    if (valid) addu(ld(r));
    int j = beg;
    for (; j + 3 < end; j += 4) {
        uint4 u0 = ld(col[j]);
        uint4 u1 = ld(col[j + 1]);
        uint4 u2 = ld(col[j + 2]);
        uint4 u3 = ld(col[j + 3]);
        p2(u0, u1);
        p2(u2, u3);
    }
    for (; j < end; ++j) addu(ld(col[j]));

    if (!valid) return;
    float di = dinv[r];
    float t0 = fmaxf(bias[fi + 0] + di * a0, 0.f);
    float t1 = fmaxf(bias[fi + 1] + di * a1, 0.f);
    float t2 = fmaxf(bias[fi + 2] + di * a2, 0.f);
    float t3 = fmaxf(bias[fi + 3] + di * a3, 0.f);
    float t4 = fmaxf(bias[fi + 4] + di * a4, 0.f);
    float t5 = fmaxf(bias[fi + 5] + di * a5, 0.f);
    float t6 = fmaxf(bias[fi + 6] + di * a6, 0.f);
    float t7 = fmaxf(bias[fi + 7] + di * a7, 0.f);

#pragma unroll
    for (int c = 0; c < 11; ++c) {
        const float* wc = &Wl[fi * 11 + c];
        float p = t0 * wc[0] + t1 * wc[11] + t2 * wc[22] + t3 * wc[33]
                + t4 * wc[44] + t5 * wc[55] + t6 * wc[66] + t7 * wc[77];
        p += __shfl_xor(p, 1, 64);
        p += __shfl_xor(p, 2, 64);
        p += __shfl_xor(p, 4, 64);
        if (li == 0) out[(size_t)r * 11 + c] = p + Wl[NFEAT * 11 + c];
    }
}

extern "C" void kernel_launch(void* const* d_in, const int* in_sizes, int n_in,
                              void* d_out, int out_size, void* d_ws, size_t ws_size,
                              hipStream_t stream) {
    const float* x   = (const float*)d_in[0];
    const int*   ei  = (const int*)d_in[1];
    const float* W1  = (const float*)d_in[2];
    const float* b1  = (const float*)d_in[3];
    const float* W2  = (const float*)d_in[4];
    const float* b2  = (const float*)d_in[5];
    const float* Wfc = (const float*)d_in[6];
    const float* bfc = (const float*)d_in[7];
    float* out = (float*)d_out;

    const int Fin = 256;
    int N = in_sizes[0] / Fin;      // 100000
    int E = in_sizes[1] / 2;        // 1600000

    char* ws = (char*)d_ws;
    size_t off = 0;
    auto alloc = [&](size_t bytes) { void* p = ws + off; off = (off + bytes + 255) & ~(size_t)255; return p; };
    int*    rowptr = (int*)   alloc((size_t)(N + 1) * 4);
    float*  dinv   = (float*) alloc((size_t)N * 4);
    int*    col    = (int*)   alloc((size_t)E * 4);
    __half* Wt1    = (__half*)alloc((size_t)64 * 256 * 2);
    __half* Wt2    = (__half*)alloc((size_t)64 * 64 * 2);
    __half* A      = (__half*)alloc((size_t)N * NFEAT * 2);  // h1 (dinv-prescaled)
    __half* H2     = (__half*)alloc((size_t)N * NFEAT * 2);  // h2 (dinv-prescaled)

    int NBKT = (N + 255) >> 8;                  // 391 buckets of 256 nodes
    int NCHK = (E + CE - 1) / CE;               // 196 chunks of 8192 edges

    int2* E2   = (int2*)alloc((size_t)E * 8);   // bucket-ordered (src,dst)
    int*  hist = (int*) alloc((size_t)NCHK * NBKT * 4);
    int*  cntB = (int*) alloc((size_t)NBKT * 4);

    int gb = (N + 63) / 64;         // 1563 (BM=64 tiles; also ag1g2 grid)
    int gA = (N + 31) / 32;         // 3125

    // prep: W converts + per-chunk histograms (no global atomics anywhere)
    k_prep<<<80 + NCHK, 256, 0, stream>>>(W1, Wt1, W2, Wt2, ei + E, hist, E, NBKT);

    // CSR chain: chunk-scan -> sorted scatter -> per-bucket CSR (+dinv)
    k_scanB<<<NBKT, 256, 0, stream>>>(hist, cntB, NCHK, NBKT);
    k_scatter<<<NCHK, 256, 0, stream>>>(ei, hist, cntB, E2, E, NBKT);
    k_csr<<<NBKT, 256, 0, stream>>>(E2, cntB, rowptr, dinv, col, N, E, NBKT);

    // layer 1 GEMM (LDS-free, barrier-free): A = fp16(dinv .* (x @ W1))
    k_gemm1<<<gb, 256, 0, stream>>>(x, Wt1, dinv, A, N);

    // FUSED layer-1 aggregate + layer-2 GEMM (degree-sorted slots)
    k_ag1g2<<<gb, 256, 0, stream>>>(A, rowptr, col, dinv, b1, Wt2, H2, N);

    // layer-2 aggregate + relu + FC -> out (degree-sorted slots)
    k_aggr2<<<gA, 256, 0, stream>>>(H2, rowptr, col, dinv, b2, Wfc, bfc, out, N);
}

// Round 8
// 327.227 us; speedup vs baseline: 4.4244x; 1.0233x over previous
//
#include <hip/hip_runtime.h>
#include <hip/hip_fp16.h>

#define NFEAT 64
#define CE 8192          // edges per histogram/scatter chunk (256 thr x 32)
#define EBUF 4608        // LDS-staged edges per bucket in k_csr

typedef _Float16 half8 __attribute__((ext_vector_type(8)));
typedef float f32x4 __attribute__((ext_vector_type(4)));

__device__ __forceinline__ __half2 bch(unsigned int u) {
    return __builtin_bit_cast(__half2, u);
}

// ---------------- prep: cvtW1 | cvtW2 | per-chunk histogram --------------------
__global__ __launch_bounds__(256) void k_prep(
    const float* __restrict__ W1, __half* __restrict__ Wt1,
    const float* __restrict__ W2, __half* __restrict__ Wt2,
    const int* __restrict__ eiDst, int* __restrict__ hist, int E, int nbkt)
{
    __shared__ int hb[512];
    int bid = blockIdx.x, tid = threadIdx.x;
    if (bid < 64) {
        int idx = bid * 256 + tid;            // [0, 16384)
        int n = idx >> 8, k = idx & 255;
        Wt1[idx] = __float2half(W1[(size_t)k * NFEAT + n]);
    } else if (bid < 80) {
        int idx = (bid - 64) * 256 + tid;     // [0, 4096)
        int n = idx >> 6, k = idx & 63;
        Wt2[idx] = __float2half(W2[(size_t)k * NFEAT + n]);
    } else {
        int c = bid - 80;
        int base = c * CE;
        if (base >= E) return;
        for (int i = tid; i < nbkt; i += 256) hb[i] = 0;
        __syncthreads();
        int hi = min(base + CE, E);
        for (int e = base + tid; e < hi; e += 256)
            atomicAdd(&hb[eiDst[e] >> 8], 1);
        __syncthreads();
        for (int i = tid; i < nbkt; i += 256)
            hist[(size_t)c * nbkt + i] = hb[i];
    }
}

// ---------------- scan B: per-bucket exclusive scan over chunks ----------------
__global__ __launch_bounds__(256) void k_scanB(int* __restrict__ hist,
                                               int* __restrict__ cntB,
                                               int nchk, int nbkt) {
    __shared__ int hb[256];
    int b = blockIdx.x, tid = threadIdx.x;
    int v = (tid < nchk) ? hist[(size_t)tid * nbkt + b] : 0;
    hb[tid] = v;
    __syncthreads();
    for (int off = 1; off < 256; off <<= 1) {
        int t = (tid >= off) ? hb[tid - off] : 0;
        __syncthreads();
        if (tid >= off) hb[tid] += t;
        __syncthreads();
    }
    if (tid < nchk) hist[(size_t)tid * nbkt + b] = hb[tid] - v;
    if (tid == 255) cntB[b] = hb[255];
}

// ---------------- scatter: LDS counting-sort chunk -> coalesced E2 writes ------
__global__ __launch_bounds__(256) void k_scatter(
    const int* __restrict__ ei, const int* __restrict__ hist,
    const int* __restrict__ cntB, int2* __restrict__ E2, int E, int nbkt)
{
    __shared__ int2 ebuf[CE];       // 64 KB
    __shared__ int lofs[512];       // local (in-chunk) exclusive bucket offsets
    __shared__ int gbase[512];      // global dest base per bucket
    __shared__ int cur[512];        // cursors / local histogram
    __shared__ int hb[256];
    int c = blockIdx.x, tid = threadIdx.x;
    int base = c * CE, hi = min(base + CE, E), ne = hi - base;

    // 1) local histogram into cur
    for (int i = tid; i < nbkt; i += 256) cur[i] = 0;
    __syncthreads();
    for (int e = base + tid; e < hi; e += 256)
        atomicAdd(&cur[ei[(size_t)E + e] >> 8], 1);
    __syncthreads();

    // 2) scan local histogram -> lofs (exclusive)
    int i0 = 2 * tid, i1 = 2 * tid + 1;
    int a0 = (i0 < nbkt) ? cur[i0] : 0;
    int a1 = (i1 < nbkt) ? cur[i1] : 0;
    hb[tid] = a0 + a1;
    __syncthreads();
    for (int off = 1; off < 256; off <<= 1) {
        int t = (tid >= off) ? hb[tid - off] : 0;
        __syncthreads();
        if (tid >= off) hb[tid] += t;
        __syncthreads();
    }
    int excl = hb[tid] - (a0 + a1);
    if (i0 < nbkt) lofs[i0] = excl;
    if (i1 < nbkt) lofs[i1] = excl + a0;

    // 3) scan cntB -> bucket bases; gbase[b] = bb[b] + hist_excl[c][b]
    int b0 = (i0 < nbkt) ? cntB[i0] : 0;
    int b1 = (i1 < nbkt) ? cntB[i1] : 0;
    hb[tid] = b0 + b1;
    __syncthreads();
    for (int off = 1; off < 256; off <<= 1) {
        int t = (tid >= off) ? hb[tid - off] : 0;
        __syncthreads();
        if (tid >= off) hb[tid] += t;
        __syncthreads();
    }
    int excl2 = hb[tid] - (b0 + b1);
    if (i0 < nbkt) gbase[i0] = excl2 + hist[(size_t)c * nbkt + i0];
    if (i1 < nbkt) gbase[i1] = excl2 + b0 + hist[(size_t)c * nbkt + i1];

    // 4) place edges into ebuf bucket-sorted (cursors = lofs copy)
    for (int i = tid; i < nbkt; i += 256) cur[i] = lofs[i];
    __syncthreads();
    for (int e = base + tid; e < hi; e += 256) {
        int s = ei[e];
        int d = ei[(size_t)E + e];
        int p = atomicAdd(&cur[d >> 8], 1);
        ebuf[p] = make_int2(s, d);
    }
    __syncthreads();

    // 5) coalesced write-out: consecutive i in a bucket -> consecutive global
    for (int i = tid; i < ne; i += 256) {
        int2 e = ebuf[i];
        int b = e.y >> 8;
        E2[gbase[b] + (i - lofs[b])] = e;
    }
}

// ---------------- csr: per-bucket CSR build + dinv -----------------------------
__global__ __launch_bounds__(256) void k_csr(
    const int2* __restrict__ E2, const int* __restrict__ cntB,
    int* __restrict__ rowptr, float* __restrict__ dinv, int* __restrict__ col,
    int N, int E, int nbkt)
{
    __shared__ int2 ebuf[EBUF];     // 36.9 KB
    __shared__ int cnt[256];
    __shared__ float dl[256];
    __shared__ int bbL[512];
    __shared__ int hb[256];
    int b = blockIdx.x, tid = threadIdx.x;

    // bucket-base scan
    int i0 = 2 * tid, i1 = 2 * tid + 1;
    int a0 = (i0 < nbkt) ? cntB[i0] : 0;
    int a1 = (i1 < nbkt) ? cntB[i1] : 0;
    hb[tid] = a0 + a1;
    __syncthreads();
    for (int off = 1; off < 256; off <<= 1) {
        int t = (tid >= off) ? hb[tid - off] : 0;
        __syncthreads();
        if (tid >= off) hb[tid] += t;
        __syncthreads();
    }
    int excl = hb[tid] - (a0 + a1);
    if (i0 < nbkt) bbL[i0] = excl;
    if (i1 < nbkt) bbL[i1] = excl + a0;
    __syncthreads();

    int e0 = bbL[b];
    int e1 = (b == nbkt - 1) ? E : bbL[b + 1];
    int ne = e1 - e0;
    int nL = min(ne, EBUF);

    cnt[tid] = 0;
    __syncthreads();
    for (int i = tid; i < nL; i += 256) {
        int2 e = E2[e0 + i];
        ebuf[i] = e;
        atomicAdd(&cnt[e.y & 255], 1);
    }
    for (int i = nL + tid; i < ne; i += 256) {        // overflow (p ~ 0)
        int2 e = E2[e0 + i];
        atomicAdd(&cnt[e.y & 255], 1);
    }
    __syncthreads();
    int c = cnt[tid];
    dl[tid] = rsqrtf((float)(c + 1));                  // +1 self-loop
    for (int off = 1; off < 256; off <<= 1) {
        int t = (tid >= off) ? cnt[tid - off] : 0;
        __syncthreads();
        if (tid >= off) cnt[tid] += t;
        __syncthreads();
    }
    int texcl = cnt[tid] - c;
    int node = b * 256 + tid;
    if (node < N) {
        rowptr[node] = e0 + texcl;
        dinv[node] = dl[tid];
    }
    if (b == 0 && tid == 0) rowptr[N] = E;
    __syncthreads();
    cnt[tid] = texcl;                                  // placement cursor
    __syncthreads();
    for (int i = tid; i < nL; i += 256) {
        int2 e = ebuf[i];
        int p = atomicAdd(&cnt[e.y & 255], 1);
        col[e0 + p] = e.x;
    }
    for (int i = nL + tid; i < ne; i += 256) {
        int2 e = E2[e0 + i];
        int p = atomicAdd(&cnt[e.y & 255], 1);
        col[e0 + p] = e.x;
    }
}

// ---------------- layer-1 GEMM: direct MFMA, deep-prefetch ---------------------
// R7 diagnosis: VGPR_Count=48 -> only ~2 of the 16 x-loads in flight; kernel was
// a serial latency chain (62us, HBM 13%). Fix: issue ALL 16 row-loads into
// statically-indexed registers first (64 VGPR), then convert+MFMA. 16-way MLP
// per lane x 16 waves/CU.
__global__ __launch_bounds__(256) void k_gemm1(
    const float* __restrict__ A, const __half* __restrict__ Wt,
    const float* __restrict__ dinv, __half* __restrict__ H, int M)
{
    const int K = 256;
    int tid = threadIdx.x;
    int w = tid >> 6, lane = tid & 63;
    int q = lane >> 4, n16 = lane & 15;
    int m0 = blockIdx.x * 64;

    int arow = m0 + w * 16 + n16;
    if (arow > M - 1) arow = M - 1;        // clamp: rows >= M never stored
    const float* ap = A + (size_t)arow * K + q * 8;
    const __half* wp = Wt + (size_t)n16 * K + q * 8;   // L1-hot W fragments

    // phase 1: issue all 16 independent x-loads (64 VGPR, static indexing)
    float4 xa[16];
#pragma unroll
    for (int kt = 0; kt < 8; ++kt) {
        xa[2 * kt]     = *(const float4*)(ap + kt * 32);
        xa[2 * kt + 1] = *(const float4*)(ap + kt * 32 + 4);
    }

    f32x4 acc[4];
#pragma unroll
    for (int nt = 0; nt < 4; ++nt) acc[nt] = (f32x4)(0.f);

    // phase 2: convert + MFMA (W loads are L1 hits, interleave freely)
#pragma unroll
    for (int kt = 0; kt < 8; ++kt) {
        float4 f0 = xa[2 * kt];
        float4 f1 = xa[2 * kt + 1];
        float fv[8] = {f0.x, f0.y, f0.z, f0.w, f1.x, f1.y, f1.z, f1.w};
        half8 ahi, alo;
#pragma unroll
        for (int j = 0; j < 8; ++j) {
            _Float16 hi = (_Float16)fv[j];
            ahi[j] = hi;
            alo[j] = (_Float16)(fv[j] - (float)hi);
        }
#pragma unroll
        for (int nt = 0; nt < 4; ++nt) {
            uint4 u = *(const uint4*)(wp + (size_t)(nt * 16) * K + kt * 32);
            half8 b = __builtin_bit_cast(half8, u);
            acc[nt] = __builtin_amdgcn_mfma_f32_16x16x32_f16(ahi, b, acc[nt], 0, 0, 0);
            acc[nt] = __builtin_amdgcn_mfma_f32_16x16x32_f16(alo, b, acc[nt], 0, 0, 0);
        }
    }

#pragma unroll
    for (int reg = 0; reg < 4; ++reg) {
        int row = m0 + w * 16 + q * 4 + reg;
        if (row < M) {
            float di = dinv[row];
#pragma unroll
            for (int nt = 0; nt < 4; ++nt)
                H[(size_t)row * NFEAT + nt * 16 + n16] =
                    __float2half(di * acc[nt][reg]);
        }
    }
}

// ---------------- FUSED: layer-1 aggregate (into LDS) + layer-2 GEMM -----------
// 8 gather-loads in flight per slot (mean degree 16 -> typically 2 batches).
__global__ __launch_bounds__(256) void k_ag1g2(
    const __half* __restrict__ h, const int* __restrict__ rowptr,
    const int* __restrict__ col, const float* __restrict__ dinv,
    const float* __restrict__ b1, const __half* __restrict__ Wt2,
    __half* __restrict__ H2, int n)
{
    __shared__ float Bs[64][68];    // 17.4 KB, stride 68 -> b128 quad-bank-clean
    __shared__ int rpb[65];
    int tid = threadIdx.x;
    int w = tid >> 6, lane = tid & 63;
    int li = lane & 7, fi = li << 3;
    int slot = (w << 3) | (lane >> 3);

    if (tid < 65) {
        int r = blockIdx.x * 64 + tid;
        rpb[tid] = rowptr[min(r, n)];
    }
    __syncthreads();

    const __half* hp = h + fi;
    auto ld = [&](int src) { return *(const uint4*)(hp + (size_t)src * NFEAT); };

#pragma unroll
    for (int hf = 0; hf < 2; ++hf) {
        int lr = hf * 32 + slot;
        int r = blockIdx.x * 64 + lr;
        float t0 = 0.f, t1 = 0.f, t2 = 0.f, t3 = 0.f,
              t4 = 0.f, t5 = 0.f, t6 = 0.f, t7 = 0.f;
        if (r < n) {
            float a0 = 0.f, a1 = 0.f, a2 = 0.f, a3 = 0.f,
                  a4 = 0.f, a5 = 0.f, a6 = 0.f, a7 = 0.f;
            auto addu = [&](uint4 u) {
                float2 f0 = __half22float2(bch(u.x));
                float2 f1 = __half22float2(bch(u.y));
                float2 f2 = __half22float2(bch(u.z));
                float2 f3 = __half22float2(bch(u.w));
                a0 += f0.x; a1 += f0.y; a2 += f1.x; a3 += f1.y;
                a4 += f2.x; a5 += f2.y; a6 += f3.x; a7 += f3.y;
            };
            auto p2 = [&](uint4 u0, uint4 u1) {
                uint4 s;
                s.x = __builtin_bit_cast(unsigned int, __hadd2(bch(u0.x), bch(u1.x)));
                s.y = __builtin_bit_cast(unsigned int, __hadd2(bch(u0.y), bch(u1.y)));
                s.z = __builtin_bit_cast(unsigned int, __hadd2(bch(u0.z), bch(u1.z)));
                s.w = __builtin_bit_cast(unsigned int, __hadd2(bch(u0.w), bch(u1.w)));
                addu(s);
            };
            int beg = rpb[lr], end = rpb[lr + 1];
            addu(ld(r));                                   // self-loop
            int j = beg;
            for (; j + 7 < end; j += 8) {                  // 8 loads in flight
                uint4 u0 = ld(col[j]);
                uint4 u1 = ld(col[j + 1]);
                uint4 u2 = ld(col[j + 2]);
                uint4 u3 = ld(col[j + 3]);
                uint4 u4 = ld(col[j + 4]);
                uint4 u5 = ld(col[j + 5]);
                uint4 u6 = ld(col[j + 6]);
                uint4 u7 = ld(col[j + 7]);
                p2(u0, u1); p2(u2, u3); p2(u4, u5); p2(u6, u7);
            }
            for (; j + 3 < end; j += 4) {
                uint4 u0 = ld(col[j]);
                uint4 u1 = ld(col[j + 1]);
                uint4 u2 = ld(col[j + 2]);
                uint4 u3 = ld(col[j + 3]);
                p2(u0, u1); p2(u2, u3);
            }
            for (; j < end; ++j) addu(ld(col[j]));
            float di = dinv[r];
            t0 = fmaxf(b1[fi + 0] + di * a0, 0.f);
            t1 = fmaxf(b1[fi + 1] + di * a1, 0.f);
            t2 = fmaxf(b1[fi + 2] + di * a2, 0.f);
            t3 = fmaxf(b1[fi + 3] + di * a3, 0.f);
            t4 = fmaxf(b1[fi + 4] + di * a4, 0.f);
            t5 = fmaxf(b1[fi + 5] + di * a5, 0.f);
            t6 = fmaxf(b1[fi + 6] + di * a6, 0.f);
            t7 = fmaxf(b1[fi + 7] + di * a7, 0.f);
        }
        *(float4*)&Bs[lr][fi]     = make_float4(t0, t1, t2, t3);
        *(float4*)&Bs[lr][fi + 4] = make_float4(t4, t5, t6, t7);
    }
    __syncthreads();

    // ---- phase 2: 16 rows per wave, K=64 from LDS ----
    int q = lane >> 4, n16 = lane & 15;
    f32x4 acc[4];
#pragma unroll
    for (int nt = 0; nt < 4; ++nt) acc[nt] = (f32x4)(0.f);
    const __half* wp = Wt2 + (size_t)n16 * 64 + q * 8;

#pragma unroll
    for (int kt = 0; kt < 2; ++kt) {
        const float* ap = &Bs[w * 16 + n16][kt * 32 + q * 8];
        float4 f0 = *(const float4*)ap;
        float4 f1 = *(const float4*)(ap + 4);
        float fv[8] = {f0.x, f0.y, f0.z, f0.w, f1.x, f1.y, f1.z, f1.w};
        half8 ahi, alo;
#pragma unroll
        for (int j = 0; j < 8; ++j) {
            _Float16 hi = (_Float16)fv[j];
            ahi[j] = hi;
            alo[j] = (_Float16)(fv[j] - (float)hi);
        }
#pragma unroll
        for (int nt = 0; nt < 4; ++nt) {
            uint4 u = *(const uint4*)(wp + (size_t)(nt * 16) * 64 + kt * 32);
            half8 b = __builtin_bit_cast(half8, u);
            acc[nt] = __builtin_amdgcn_mfma_f32_16x16x32_f16(ahi, b, acc[nt], 0, 0, 0);
            acc[nt] = __builtin_amdgcn_mfma_f32_16x16x32_f16(alo, b, acc[nt], 0, 0, 0);
        }
    }
#pragma unroll
    for (int reg = 0; reg < 4; ++reg) {
        int row = blockIdx.x * 64 + w * 16 + q * 4 + reg;
        if (row < n) {
            float di = dinv[row];
#pragma unroll
            for (int nt = 0; nt < 4; ++nt)
                H2[(size_t)row * NFEAT + nt * 16 + n16] =
                    __float2half(di * acc[nt][reg]);
        }
    }
}

// ---------------- layer-2 aggregate + relu + FC -> out [N,11] ------------------
__global__ __launch_bounds__(256) void k_aggr2(
    const __half* __restrict__ h, const int* __restrict__ rowptr,
    const int* __restrict__ col, const float* __restrict__ dinv,
    const float* __restrict__ bias, const float* __restrict__ Wfc,
    const float* __restrict__ bfc, float* __restrict__ out, int n)
{
    __shared__ float Wl[NFEAT * 11 + 11];
    int tid = threadIdx.x;
    for (int i = tid; i < NFEAT * 11; i += 256) Wl[i] = Wfc[i];
    if (tid < 11) Wl[NFEAT * 11 + tid] = bfc[tid];
    __syncthreads();

    int lane = tid & 63;
    int li = lane & 7;
    int fi = li << 3;
    int r = blockIdx.x * 32 + ((tid >> 6) << 3) + (lane >> 3);
    bool valid = r < n;

    int beg = 0, end = 0;
    if (valid) { beg = rowptr[r]; end = rowptr[r + 1]; }

    const __half* hp = h + fi;
    auto ld = [&](int src) { return *(const uint4*)(hp + (size_t)src * NFEAT); };

    float a0 = 0.f, a1 = 0.f, a2 = 0.f, a3 = 0.f,
          a4 = 0.f, a5 = 0.f, a6 = 0.f, a7 = 0.f;
    auto addu = [&](uint4 u) {
        float2 f0 = __half22float2(bch(u.x));
        float2 f1 = __half22float2(bch(u.y));
        float2 f2 = __half22float2(bch(u.z));
        float2 f3 = __half22float2(bch(u.w));
        a0 += f0.x; a1 += f0.y; a2 += f1.x; a3 += f1.y;
        a4 += f2.x; a5 += f2.y; a6 += f3.x; a7 += f3.y;
    };
    auto p2 = [&](uint4 u0, uint4 u1) {
        uint4 s;
        s.x = __builtin_bit_cast(unsigned int, __hadd2(bch(u0.x), bch(u1.x)));
        s.y = __builtin_bit_cast(unsigned int, __hadd2(bch(u0.y), bch(u1.y)));
        s.z = __builtin_bit_cast(unsigned int, __hadd2(bch(u0.z), bch(u1.z)));
        s.w = __builtin_bit_cast(unsigned int, __hadd2(bch(u0.w), bch(u1.w)));
        addu(s);
    };

    if (valid) addu(ld(r));
    int j = beg;
    for (; j + 7 < end; j += 8) {
        uint4 u0 = ld(col[j]);
        uint4 u1 = ld(col[j + 1]);
        uint4 u2 = ld(col[j + 2]);
        uint4 u3 = ld(col[j + 3]);
        uint4 u4 = ld(col[j + 4]);
        uint4 u5 = ld(col[j + 5]);
        uint4 u6 = ld(col[j + 6]);
        uint4 u7 = ld(col[j + 7]);
        p2(u0, u1); p2(u2, u3); p2(u4, u5); p2(u6, u7);
    }
    for (; j + 3 < end; j += 4) {
        uint4 u0 = ld(col[j]);
        uint4 u1 = ld(col[j + 1]);
        uint4 u2 = ld(col[j + 2]);
        uint4 u3 = ld(col[j + 3]);
        p2(u0, u1); p2(u2, u3);
    }
    for (; j < end; ++j) addu(ld(col[j]));

    if (!valid) return;
    float di = dinv[r];
    float t0 = fmaxf(bias[fi + 0] + di * a0, 0.f);
    float t1 = fmaxf(bias[fi + 1] + di * a1, 0.f);
    float t2 = fmaxf(bias[fi + 2] + di * a2, 0.f);
    float t3 = fmaxf(bias[fi + 3] + di * a3, 0.f);
    float t4 = fmaxf(bias[fi + 4] + di * a4, 0.f);
    float t5 = fmaxf(bias[fi + 5] + di * a5, 0.f);
    float t6 = fmaxf(bias[fi + 6] + di * a6, 0.f);
    float t7 = fmaxf(bias[fi + 7] + di * a7, 0.f);

#pragma unroll
    for (int c = 0; c < 11; ++c) {
        const float* wc = &Wl[fi * 11 + c];
        float p = t0 * wc[0] + t1 * wc[11] + t2 * wc[22] + t3 * wc[33]
                + t4 * wc[44] + t5 * wc[55] + t6 * wc[66] + t7 * wc[77];
        p += __shfl_xor(p, 1, 64);
        p += __shfl_xor(p, 2, 64);
        p += __shfl_xor(p, 4, 64);
        if (li == 0) out[(size_t)r * 11 + c] = p + Wl[NFEAT * 11 + c];
    }
}

extern "C" void kernel_launch(void* const* d_in, const int* in_sizes, int n_in,
                              void* d_out, int out_size, void* d_ws, size_t ws_size,
                              hipStream_t stream) {
    const float* x   = (const float*)d_in[0];
    const int*   ei  = (const int*)d_in[1];
    const float* W1  = (const float*)d_in[2];
    const float* b1  = (const float*)d_in[3];
    const float* W2  = (const float*)d_in[4];
    const float* b2  = (const float*)d_in[5];
    const float* Wfc = (const float*)d_in[6];
    const float* bfc = (const float*)d_in[7];
    float* out = (float*)d_out;

    const int Fin = 256;
    int N = in_sizes[0] / Fin;      // 100000
    int E = in_sizes[1] / 2;        // 1600000

    char* ws = (char*)d_ws;
    size_t off = 0;
    auto alloc = [&](size_t bytes) { void* p = ws + off; off = (off + bytes + 255) & ~(size_t)255; return p; };
    int*    rowptr = (int*)   alloc((size_t)(N + 1) * 4);
    float*  dinv   = (float*) alloc((size_t)N * 4);
    int*    col    = (int*)   alloc((size_t)E * 4);
    __half* Wt1    = (__half*)alloc((size_t)64 * 256 * 2);
    __half* Wt2    = (__half*)alloc((size_t)64 * 64 * 2);
    __half* A      = (__half*)alloc((size_t)N * NFEAT * 2);  // h1 (dinv-prescaled)
    __half* H2     = (__half*)alloc((size_t)N * NFEAT * 2);  // h2 (dinv-prescaled)

    int NBKT = (N + 255) >> 8;                  // 391 buckets of 256 nodes
    int NCHK = (E + CE - 1) / CE;               // 196 chunks of 8192 edges

    int2* E2   = (int2*)alloc((size_t)E * 8);   // bucket-ordered (src,dst)
    int*  hist = (int*) alloc((size_t)NCHK * NBKT * 4);
    int*  cntB = (int*) alloc((size_t)NBKT * 4);

    int gb = (N + 63) / 64;         // 1563 (BM=64 tiles; also ag1g2 grid)
    int gA = (N + 31) / 32;         // 3125

    // prep: W converts + per-chunk histograms (no global atomics anywhere)
    k_prep<<<80 + NCHK, 256, 0, stream>>>(W1, Wt1, W2, Wt2, ei + E, hist, E, NBKT);

    // CSR chain: chunk-scan -> sorted scatter -> per-bucket CSR (+dinv)
    k_scanB<<<NBKT, 256, 0, stream>>>(hist, cntB, NCHK, NBKT);
    k_scatter<<<NCHK, 256, 0, stream>>>(ei, hist, cntB, E2, E, NBKT);
    k_csr<<<NBKT, 256, 0, stream>>>(E2, cntB, rowptr, dinv, col, N, E, NBKT);

    // layer 1 GEMM (deep-prefetch direct MFMA): A = fp16(dinv .* (x @ W1))
    k_gemm1<<<gb, 256, 0, stream>>>(x, Wt1, dinv, A, N);

    // FUSED layer-1 aggregate + layer-2 GEMM
    k_ag1g2<<<gb, 256, 0, stream>>>(A, rowptr, col, dinv, b1, Wt2, H2, N);

    // layer-2 aggregate + relu + FC -> out
    k_aggr2<<<gA, 256, 0, stream>>>(H2, rowptr, col, dinv, b2, Wfc, bfc, out, N);
}